// Round 4
// baseline (192.746 us; speedup 1.0000x reference)
//
#include <hip/hip_runtime.h>
#include <hip/hip_bf16.h>

// IsolaCLIPLoss: out = 3*align + 0.5*(log-mean-exp uniformity of img Gram + txt Gram)
// N=8192, D=512 fp32 inputs.
//
// R4 changes vs R3:
//  - LDS swizzle swz(r) = (r ^ (r>>3)) & 7: distinct chunks for rows 16 apart
//    (kills the 1024-conflict-cycles/block from lane groups {L,L+16,L+32,L+48};
//    old (r&7) swizzle repeats with period 8).
//  - finalize fused into gram via done-counter; last block's wave 0 reduces
//    the spread S accumulators (atomic reads) + alignp partials and writes out.
//    3 graph nodes instead of 4.

#define NROWS 8192
#define DBYTES 512         // row stride in bytes (fp8) == D
#define NT    64           // 8192/128 tiles per dim
#define NTILES 2080        // NT*(NT+1)/2 upper-triangular tiles
#define NBLOCKS_TOTAL (NTILES * 2)
#define SCALE_SPLAT 0x75757575  // E8M0 byte 117 = 2^-10, splatted

typedef __attribute__((ext_vector_type(8)))  int   int8v;
typedef __attribute__((ext_vector_type(4)))  int   int4v;
typedef __attribute__((ext_vector_type(16))) float float16v;

__device__ inline void load_lds16(const void* g, void* l) {
    __builtin_amdgcn_global_load_lds(
        (const __attribute__((address_space(1))) void*)g,
        (__attribute__((address_space(3))) void*)l, 16, 0, 0);
}

__device__ inline int swz(int r) { return (r ^ (r >> 3)) & 7; }

// ---------------------------------------------------------------- normalize
// 4 rows per block (one per wave). fp32 float4 loads, shuffle reduce,
// quantize to e4m3 * 2^10, 4B int stores. Align partial per block.
__global__ __launch_bounds__(256) void normalize_kernel(
    const float* __restrict__ img, const float* __restrict__ txt,
    unsigned char* __restrict__ nimg, unsigned char* __restrict__ ntxt,
    float* __restrict__ alignp)   // [2048] per-block partial of sum_i ndot_i
{
    const int lane = threadIdx.x & 63;
    const int wave = threadIdx.x >> 6;
    const int row  = blockIdx.x * 4 + wave;

    const float4* pi = (const float4*)(img + (size_t)row * 512);
    const float4* pt = (const float4*)(txt + (size_t)row * 512);
    const float4 i0 = pi[lane], i1 = pi[lane + 64];
    const float4 t0 = pt[lane], t1 = pt[lane + 64];

    float ssi = i0.x*i0.x + i0.y*i0.y + i0.z*i0.z + i0.w*i0.w
              + i1.x*i1.x + i1.y*i1.y + i1.z*i1.z + i1.w*i1.w;
    float sst = t0.x*t0.x + t0.y*t0.y + t0.z*t0.z + t0.w*t0.w
              + t1.x*t1.x + t1.y*t1.y + t1.z*t1.z + t1.w*t1.w;
    float dot = i0.x*t0.x + i0.y*t0.y + i0.z*t0.z + i0.w*t0.w
              + i1.x*t1.x + i1.y*t1.y + i1.z*t1.z + i1.w*t1.w;

    #pragma unroll
    for (int off = 1; off < 64; off <<= 1) {
        ssi += __shfl_xor(ssi, off);
        sst += __shfl_xor(sst, off);
        dot += __shfl_xor(dot, off);
    }
    const float inv_i = 1.0f / fmaxf(sqrtf(ssi), 1e-12f);
    const float inv_t = 1.0f / fmaxf(sqrtf(sst), 1e-12f);
    const float si = 1024.0f * inv_i;   // quantize at 2^10 scale
    const float st = 1024.0f * inv_t;

    int p0 = __builtin_amdgcn_cvt_pk_fp8_f32(i0.x*si, i0.y*si, 0, false);
    p0     = __builtin_amdgcn_cvt_pk_fp8_f32(i0.z*si, i0.w*si, p0, true);
    int p1 = __builtin_amdgcn_cvt_pk_fp8_f32(i1.x*si, i1.y*si, 0, false);
    p1     = __builtin_amdgcn_cvt_pk_fp8_f32(i1.z*si, i1.w*si, p1, true);
    int q0 = __builtin_amdgcn_cvt_pk_fp8_f32(t0.x*st, t0.y*st, 0, false);
    q0     = __builtin_amdgcn_cvt_pk_fp8_f32(t0.z*st, t0.w*st, q0, true);
    int q1 = __builtin_amdgcn_cvt_pk_fp8_f32(t1.x*st, t1.y*st, 0, false);
    q1     = __builtin_amdgcn_cvt_pk_fp8_f32(t1.z*st, t1.w*st, q1, true);

    int* oi = (int*)(nimg + (size_t)row * DBYTES);
    int* ot = (int*)(ntxt + (size_t)row * DBYTES);
    oi[lane] = p0; oi[lane + 64] = p1;
    ot[lane] = q0; ot[lane + 64] = q1;

    __shared__ float r4[4];
    if (lane == 0) r4[wave] = dot * inv_i * inv_t;
    __syncthreads();
    if (threadIdx.x == 0)
        alignp[blockIdx.x] = r4[0] + r4[1] + r4[2] + r4[3];
}

// ---------------------------------------------------------------- gram + lme
// 128x128 tile per block, 4 waves in 2x2 (each wave 64x64 via 2x2 of 32x32
// MX-fp8 MFMA, K=64 per instruction). BK=128 bytes staged per iteration.
// LDS tile [128 rows][8 chunks of 16B], physical chunk = chunk ^ swz(row).
// Last block (done-counter) reduces S + alignp and writes the final scalar.
__global__ __launch_bounds__(256) void gram_kernel(
    const unsigned char* __restrict__ A0,   // fp8 [8192][512], blockIdx.y==0
    const unsigned char* __restrict__ A1,   // blockIdx.y==1
    float* __restrict__ S,                  // [64] spread accumulators
    int* __restrict__ done,                 // [1] block completion counter
    const float* __restrict__ alignp,       // [2048] from normalize
    float* __restrict__ out)
{
    // Decode upper-triangular tile index t -> (i, j), i <= j.
    const int t = blockIdx.x;
    int i = (int)((129.0f - sqrtf(129.0f * 129.0f - 8.0f * (float)t)) * 0.5f);
    while ((i + 1) * (129 - (i + 1)) / 2 <= t) ++i;
    while (i * (129 - i) / 2 > t) --i;
    const int j = i + (t - i * (129 - i) / 2);

    const unsigned char* __restrict__ A = blockIdx.y ? A1 : A0;
    const int tid  = threadIdx.x;
    const int lane = tid & 63;
    const int wave = tid >> 6;
    const int wm = wave & 1, wn = wave >> 1;   // 2x2 wave grid over 128x128
    const int lr = lane & 31;                  // row-in-subtile
    const int h  = lane >> 5;                  // K-half select

    const unsigned char* gA = A + (size_t)i * 128 * DBYTES;
    const unsigned char* gB = A + (size_t)j * 128 * DBYTES;

    __shared__ __align__(16) unsigned char ldsA[128 * 128];   // 16 KB
    __shared__ __align__(16) unsigned char ldsB[128 * 128];   // 16 KB

    float16v acc[2][2];
    #pragma unroll
    for (int a = 0; a < 2; ++a)
        #pragma unroll
        for (int b = 0; b < 2; ++b)
            #pragma unroll
            for (int r = 0; r < 16; ++r) acc[a][b][r] = 0.0f;

    for (int k0 = 0; k0 < DBYTES; k0 += 128) {
        // Stage 128x128B of A-rows and B-rows. LDS slot lane-contiguous
        // (global_load_lds requirement); global chunk cl = cp ^ swz(r).
        #pragma unroll
        for (int rnd = 0; rnd < 4; ++rnd) {
            const int slot = rnd * 4096 + tid * 16;
            const int r    = slot >> 7;
            const int cp   = (slot >> 4) & 7;
            const int cl   = cp ^ swz(r);
            load_lds16(gA + (size_t)r * DBYTES + k0 + cl * 16, &ldsA[slot]);
            load_lds16(gB + (size_t)r * DBYTES + k0 + cl * 16, &ldsB[slot]);
        }
        __syncthreads();

        #pragma unroll
        for (int kk = 0; kk < 2; ++kk) {       // two K=64 steps per stage
            const int cbase = kk * 4 + h * 2;  // logical 16B chunk, this lane
            int8v av[2], bv[2];
            #pragma unroll
            for (int mt = 0; mt < 2; ++mt) {
                const int r = wm * 64 + mt * 32 + lr;
                const int s = swz(r);
                const int4v q0 = *(const int4v*)&ldsA[r * 128 + ((cbase    ) ^ s) * 16];
                const int4v q1 = *(const int4v*)&ldsA[r * 128 + ((cbase + 1) ^ s) * 16];
                av[mt][0]=q0[0]; av[mt][1]=q0[1]; av[mt][2]=q0[2]; av[mt][3]=q0[3];
                av[mt][4]=q1[0]; av[mt][5]=q1[1]; av[mt][6]=q1[2]; av[mt][7]=q1[3];
            }
            #pragma unroll
            for (int nt = 0; nt < 2; ++nt) {
                const int r = wn * 64 + nt * 32 + lr;
                const int s = swz(r);
                const int4v q0 = *(const int4v*)&ldsB[r * 128 + ((cbase    ) ^ s) * 16];
                const int4v q1 = *(const int4v*)&ldsB[r * 128 + ((cbase + 1) ^ s) * 16];
                bv[nt][0]=q0[0]; bv[nt][1]=q0[1]; bv[nt][2]=q0[2]; bv[nt][3]=q0[3];
                bv[nt][4]=q1[0]; bv[nt][5]=q1[1]; bv[nt][6]=q1[2]; bv[nt][7]=q1[3];
            }
            #pragma unroll
            for (int mt = 0; mt < 2; ++mt)
                #pragma unroll
                for (int nt = 0; nt < 2; ++nt)
                    acc[mt][nt] = __builtin_amdgcn_mfma_scale_f32_32x32x64_f8f6f4(
                        av[mt], bv[nt], acc[mt][nt],
                        0, 0,                       // cbsz=fp8(e4m3), blgp=fp8
                        0, SCALE_SPLAT,             // opsel_a, scale_a (2^-10)
                        0, SCALE_SPLAT);            // opsel_b, scale_b (2^-10)
        }
        __syncthreads();
    }

    // Epilogue: sum exp(4*min(G,1)-4); tile-sum is layout-invariant.
    float s = 0.0f;
    #pragma unroll
    for (int mt = 0; mt < 2; ++mt)
        #pragma unroll
        for (int nt = 0; nt < 2; ++nt)
            #pragma unroll
            for (int r2 = 0; r2 < 16; ++r2) {
                const float g = acc[mt][nt][r2];
                s += __expf(4.0f * fminf(g, 1.0f) - 4.0f);
            }
    #pragma unroll
    for (int off = 32; off; off >>= 1) s += __shfl_down(s, off);
    __shared__ float ps[4];
    __shared__ int is_last;
    if (lane == 0) ps[wave] = s;
    __syncthreads();
    if (tid == 0) {
        const float tot = ps[0] + ps[1] + ps[2] + ps[3];
        const float w = (i == j) ? 1.0f : 2.0f;   // symmetry weight
        atomicAdd(&S[blockIdx.y * 32 + (blockIdx.x & 31)], tot * w);
        __threadfence();                           // order S-add before done-add
        const int old = atomicAdd(done, 1);
        is_last = (old == NBLOCKS_TOTAL - 1) ? 1 : 0;
    }
    __syncthreads();

    if (is_last && wave == 0) {
        // Final reduction by one wave: S via atomic reads (same coherence
        // point as the writers), alignp via plain loads (prior dispatch).
        float sv = atomicAdd(&S[lane], 0.0f);
        #pragma unroll
        for (int off = 1; off < 32; off <<= 1) sv += __shfl_xor(sv, off);
        const float s_img = __shfl(sv, 0);
        const float s_txt = __shfl(sv, 32);

        float a = 0.0f;
        #pragma unroll
        for (int k = 0; k < 32; ++k) a += alignp[lane + 64 * k];
        #pragma unroll
        for (int off = 1; off < 64; off <<= 1) a += __shfl_xor(a, off);

        if (lane == 0) {
            const double align = 2.0 - 2.0 * (double)a / (double)NROWS;
            const double n2 = (double)NROWS * (double)NROWS;
            const double unif = 0.5 * (log((double)s_img / n2) + log((double)s_txt / n2));
            out[0] = (float)(3.0 * align + unif);
        }
    }
}

// ---------------------------------------------------------------- launch
extern "C" void kernel_launch(void* const* d_in, const int* in_sizes, int n_in,
                              void* d_out, int out_size, void* d_ws, size_t ws_size,
                              hipStream_t stream) {
    const float* img = (const float*)d_in[0];
    const float* txt = (const float*)d_in[1];
    char* ws = (char*)d_ws;
    unsigned char* nimg = (unsigned char*)ws;                             // 4 MB
    unsigned char* ntxt = (unsigned char*)(ws + (size_t)NROWS * DBYTES);  // 4 MB
    float* S      = (float*)(ws + 2 * (size_t)NROWS * DBYTES);            // [64]
    int*   done   = (int*)(S + 64);                                       // [1]
    float* alignp = (float*)(done + 1);                                   // [2048]

    hipMemsetAsync(S, 0, 65 * sizeof(float), stream);   // S + done
    normalize_kernel<<<NROWS / 4, 256, 0, stream>>>(img, txt, nimg, ntxt, alignp);
    dim3 grid(NTILES, 2);
    gram_kernel<<<grid, 256, 0, stream>>>(nimg, ntxt, S, done, alignp, (float*)d_out);
}

// Round 5
// 127.856 us; speedup vs baseline: 1.5075x; 1.5075x over previous
//
#include <hip/hip_runtime.h>
#include <hip/hip_bf16.h>

// IsolaCLIPLoss: out = 3*align + 0.5*(log-mean-exp uniformity of img Gram + txt Gram)
// N=8192, D=512 fp32 inputs.
//
// R5 changes vs R4:
//  - REVERT fused finalize + __threadfence (R4 regression: per-block device
//    fence invalidated per-XCD L2 -> staging loads stalled, gram 51->126 us).
//    finalize is a separate 1-block dispatch again.
//  - KEEP swz(r) = (r ^ (r>>3)) & 7 LDS swizzle (bank conflicts == 0).
//  - memset node folded into normalize (block 0 zeroes S): 3 nodes total.

#define NROWS 8192
#define DBYTES 512         // row stride in bytes (fp8) == D
#define NT    64           // 8192/128 tiles per dim
#define NTILES 2080        // NT*(NT+1)/2 upper-triangular tiles
#define SCALE_SPLAT 0x75757575  // E8M0 byte 117 = 2^-10, splatted

typedef __attribute__((ext_vector_type(8)))  int   int8v;
typedef __attribute__((ext_vector_type(4)))  int   int4v;
typedef __attribute__((ext_vector_type(16))) float float16v;

__device__ inline void load_lds16(const void* g, void* l) {
    __builtin_amdgcn_global_load_lds(
        (const __attribute__((address_space(1))) void*)g,
        (__attribute__((address_space(3))) void*)l, 16, 0, 0);
}

__device__ inline int swz(int r) { return (r ^ (r >> 3)) & 7; }

// ---------------------------------------------------------------- normalize
// 4 rows per block (one per wave). fp32 float4 loads, shuffle reduce,
// quantize to e4m3 * 2^10, 4B int stores. Align partial per block.
// Block 0 also zeroes the S accumulators (replaces the memset node).
__global__ __launch_bounds__(256) void normalize_kernel(
    const float* __restrict__ img, const float* __restrict__ txt,
    unsigned char* __restrict__ nimg, unsigned char* __restrict__ ntxt,
    float* __restrict__ alignp,   // [2048] per-block partial of sum_i ndot_i
    float* __restrict__ S)        // [64] gram accumulators -> zeroed here
{
    if (blockIdx.x == 0 && threadIdx.x < 64) S[threadIdx.x] = 0.0f;

    const int lane = threadIdx.x & 63;
    const int wave = threadIdx.x >> 6;
    const int row  = blockIdx.x * 4 + wave;

    const float4* pi = (const float4*)(img + (size_t)row * 512);
    const float4* pt = (const float4*)(txt + (size_t)row * 512);
    const float4 i0 = pi[lane], i1 = pi[lane + 64];
    const float4 t0 = pt[lane], t1 = pt[lane + 64];

    float ssi = i0.x*i0.x + i0.y*i0.y + i0.z*i0.z + i0.w*i0.w
              + i1.x*i1.x + i1.y*i1.y + i1.z*i1.z + i1.w*i1.w;
    float sst = t0.x*t0.x + t0.y*t0.y + t0.z*t0.z + t0.w*t0.w
              + t1.x*t1.x + t1.y*t1.y + t1.z*t1.z + t1.w*t1.w;
    float dot = i0.x*t0.x + i0.y*t0.y + i0.z*t0.z + i0.w*t0.w
              + i1.x*t1.x + i1.y*t1.y + i1.z*t1.z + i1.w*t1.w;

    #pragma unroll
    for (int off = 1; off < 64; off <<= 1) {
        ssi += __shfl_xor(ssi, off);
        sst += __shfl_xor(sst, off);
        dot += __shfl_xor(dot, off);
    }
    const float inv_i = 1.0f / fmaxf(sqrtf(ssi), 1e-12f);
    const float inv_t = 1.0f / fmaxf(sqrtf(sst), 1e-12f);
    const float si = 1024.0f * inv_i;   // quantize at 2^10 scale
    const float st = 1024.0f * inv_t;

    int p0 = __builtin_amdgcn_cvt_pk_fp8_f32(i0.x*si, i0.y*si, 0, false);
    p0     = __builtin_amdgcn_cvt_pk_fp8_f32(i0.z*si, i0.w*si, p0, true);
    int p1 = __builtin_amdgcn_cvt_pk_fp8_f32(i1.x*si, i1.y*si, 0, false);
    p1     = __builtin_amdgcn_cvt_pk_fp8_f32(i1.z*si, i1.w*si, p1, true);
    int q0 = __builtin_amdgcn_cvt_pk_fp8_f32(t0.x*st, t0.y*st, 0, false);
    q0     = __builtin_amdgcn_cvt_pk_fp8_f32(t0.z*st, t0.w*st, q0, true);
    int q1 = __builtin_amdgcn_cvt_pk_fp8_f32(t1.x*st, t1.y*st, 0, false);
    q1     = __builtin_amdgcn_cvt_pk_fp8_f32(t1.z*st, t1.w*st, q1, true);

    int* oi = (int*)(nimg + (size_t)row * DBYTES);
    int* ot = (int*)(ntxt + (size_t)row * DBYTES);
    oi[lane] = p0; oi[lane + 64] = p1;
    ot[lane] = q0; ot[lane + 64] = q1;

    __shared__ float r4[4];
    if (lane == 0) r4[wave] = dot * inv_i * inv_t;
    __syncthreads();
    if (threadIdx.x == 0)
        alignp[blockIdx.x] = r4[0] + r4[1] + r4[2] + r4[3];
}

// ---------------------------------------------------------------- gram + lme
// 128x128 tile per block, 4 waves in 2x2 (each wave 64x64 via 2x2 of 32x32
// MX-fp8 MFMA, K=64 per instruction). BK=128 bytes staged per iteration.
// LDS tile [128 rows][8 chunks of 16B], physical chunk = chunk ^ swz(row).
__global__ __launch_bounds__(256) void gram_kernel(
    const unsigned char* __restrict__ A0,   // fp8 [8192][512], blockIdx.y==0
    const unsigned char* __restrict__ A1,   // blockIdx.y==1
    float* __restrict__ S)                  // [64] spread accumulators
{
    // Decode upper-triangular tile index t -> (i, j), i <= j.
    const int t = blockIdx.x;
    int i = (int)((129.0f - sqrtf(129.0f * 129.0f - 8.0f * (float)t)) * 0.5f);
    while ((i + 1) * (129 - (i + 1)) / 2 <= t) ++i;
    while (i * (129 - i) / 2 > t) --i;
    const int j = i + (t - i * (129 - i) / 2);

    const unsigned char* __restrict__ A = blockIdx.y ? A1 : A0;
    const int tid  = threadIdx.x;
    const int lane = tid & 63;
    const int wave = tid >> 6;
    const int wm = wave & 1, wn = wave >> 1;   // 2x2 wave grid over 128x128
    const int lr = lane & 31;                  // row-in-subtile
    const int h  = lane >> 5;                  // K-half select

    const unsigned char* gA = A + (size_t)i * 128 * DBYTES;
    const unsigned char* gB = A + (size_t)j * 128 * DBYTES;

    __shared__ __align__(16) unsigned char ldsA[128 * 128];   // 16 KB
    __shared__ __align__(16) unsigned char ldsB[128 * 128];   // 16 KB

    float16v acc[2][2];
    #pragma unroll
    for (int a = 0; a < 2; ++a)
        #pragma unroll
        for (int b = 0; b < 2; ++b)
            #pragma unroll
            for (int r = 0; r < 16; ++r) acc[a][b][r] = 0.0f;

    for (int k0 = 0; k0 < DBYTES; k0 += 128) {
        // Stage 128x128B of A-rows and B-rows. LDS slot lane-contiguous
        // (global_load_lds requirement); global chunk cl = cp ^ swz(r).
        #pragma unroll
        for (int rnd = 0; rnd < 4; ++rnd) {
            const int slot = rnd * 4096 + tid * 16;
            const int r    = slot >> 7;
            const int cp   = (slot >> 4) & 7;
            const int cl   = cp ^ swz(r);
            load_lds16(gA + (size_t)r * DBYTES + k0 + cl * 16, &ldsA[slot]);
            load_lds16(gB + (size_t)r * DBYTES + k0 + cl * 16, &ldsB[slot]);
        }
        __syncthreads();

        #pragma unroll
        for (int kk = 0; kk < 2; ++kk) {       // two K=64 steps per stage
            const int cbase = kk * 4 + h * 2;  // logical 16B chunk, this lane
            int8v av[2], bv[2];
            #pragma unroll
            for (int mt = 0; mt < 2; ++mt) {
                const int r = wm * 64 + mt * 32 + lr;
                const int s = swz(r);
                const int4v q0 = *(const int4v*)&ldsA[r * 128 + ((cbase    ) ^ s) * 16];
                const int4v q1 = *(const int4v*)&ldsA[r * 128 + ((cbase + 1) ^ s) * 16];
                av[mt][0]=q0[0]; av[mt][1]=q0[1]; av[mt][2]=q0[2]; av[mt][3]=q0[3];
                av[mt][4]=q1[0]; av[mt][5]=q1[1]; av[mt][6]=q1[2]; av[mt][7]=q1[3];
            }
            #pragma unroll
            for (int nt = 0; nt < 2; ++nt) {
                const int r = wn * 64 + nt * 32 + lr;
                const int s = swz(r);
                const int4v q0 = *(const int4v*)&ldsB[r * 128 + ((cbase    ) ^ s) * 16];
                const int4v q1 = *(const int4v*)&ldsB[r * 128 + ((cbase + 1) ^ s) * 16];
                bv[nt][0]=q0[0]; bv[nt][1]=q0[1]; bv[nt][2]=q0[2]; bv[nt][3]=q0[3];
                bv[nt][4]=q1[0]; bv[nt][5]=q1[1]; bv[nt][6]=q1[2]; bv[nt][7]=q1[3];
            }
            #pragma unroll
            for (int mt = 0; mt < 2; ++mt)
                #pragma unroll
                for (int nt = 0; nt < 2; ++nt)
                    acc[mt][nt] = __builtin_amdgcn_mfma_scale_f32_32x32x64_f8f6f4(
                        av[mt], bv[nt], acc[mt][nt],
                        0, 0,                       // cbsz=fp8(e4m3), blgp=fp8
                        0, SCALE_SPLAT,             // opsel_a, scale_a (2^-10)
                        0, SCALE_SPLAT);            // opsel_b, scale_b (2^-10)
        }
        __syncthreads();
    }

    // Epilogue: sum exp(4*min(G,1)-4); tile-sum is layout-invariant.
    float s = 0.0f;
    #pragma unroll
    for (int mt = 0; mt < 2; ++mt)
        #pragma unroll
        for (int nt = 0; nt < 2; ++nt)
            #pragma unroll
            for (int r2 = 0; r2 < 16; ++r2) {
                const float g = acc[mt][nt][r2];
                s += __expf(4.0f * fminf(g, 1.0f) - 4.0f);
            }
    #pragma unroll
    for (int off = 32; off; off >>= 1) s += __shfl_down(s, off);
    __shared__ float ps[4];
    if (lane == 0) ps[wave] = s;
    __syncthreads();
    if (tid == 0) {
        const float tot = ps[0] + ps[1] + ps[2] + ps[3];
        const float w = (i == j) ? 1.0f : 2.0f;   // symmetry weight
        atomicAdd(&S[blockIdx.y * 32 + (blockIdx.x & 31)], tot * w);
    }
}

// ---------------------------------------------------------------- finalize
__global__ __launch_bounds__(256) void finalize_kernel(
    const float* __restrict__ S,       // [64]
    const float* __restrict__ alignp,  // [2048]
    float* __restrict__ out)
{
    const int tid = threadIdx.x;
    float a = 0.0f;
    #pragma unroll
    for (int k = 0; k < 8; ++k) a += alignp[tid + 256 * k];
    #pragma unroll
    for (int off = 32; off; off >>= 1) a += __shfl_down(a, off);
    __shared__ float r4[4];
    if ((tid & 63) == 0) r4[tid >> 6] = a;
    __syncthreads();
    if (tid == 0) {
        const double A = (double)r4[0] + r4[1] + r4[2] + r4[3];
        double si = 0.0, st = 0.0;
        for (int k = 0; k < 32; ++k) { si += S[k]; st += S[32 + k]; }
        const double align = 2.0 - 2.0 * A / (double)NROWS;
        const double n2 = (double)NROWS * (double)NROWS;
        const double unif = 0.5 * (log(si / n2) + log(st / n2));
        out[0] = (float)(3.0 * align + unif);
    }
}

// ---------------------------------------------------------------- launch
extern "C" void kernel_launch(void* const* d_in, const int* in_sizes, int n_in,
                              void* d_out, int out_size, void* d_ws, size_t ws_size,
                              hipStream_t stream) {
    const float* img = (const float*)d_in[0];
    const float* txt = (const float*)d_in[1];
    char* ws = (char*)d_ws;
    unsigned char* nimg = (unsigned char*)ws;                             // 4 MB
    unsigned char* ntxt = (unsigned char*)(ws + (size_t)NROWS * DBYTES);  // 4 MB
    float* S      = (float*)(ws + 2 * (size_t)NROWS * DBYTES);            // [64]
    float* alignp = S + 64;                                               // [2048]

    normalize_kernel<<<NROWS / 4, 256, 0, stream>>>(img, txt, nimg, ntxt, alignp, S);
    dim3 grid(NTILES, 2);
    gram_kernel<<<grid, 256, 0, stream>>>(nimg, ntxt, S);
    finalize_kernel<<<1, 256, 0, stream>>>(S, alignp, (float*)d_out);
}